// Round 1
// baseline (131.896 us; speedup 1.0000x reference)
//
#include <hip/hip_runtime.h>

// AnnularDilatedKNN: B=4, N=4096, C=64, SAMPLE=16, DILATED_RATE=2, r^2=256.
// Round 4: grid-hashed ball query.
//  - Uniform grid, cell=16 (=radius), 20^3 cells over [-160,160)^3 (clamped;
//    clamping only adds false positives, distance test filters).
//  - Points cell-sorted (histogram -> scan -> scatter). Query wave scans only
//    the 3x3x3 neighborhood (~6.4x ball volume ~ 370 candidates avg vs 4096),
//    sets hit bits in a 4096-bit LDS mask indexed by ORIGINAL index, then
//    recovers ranks exactly via popcount + wave shuffle-scan.
//  - Hit test is bit-identical to previous rounds: sq=(x*x+y*y)+z*z,
//    dot=(xi*xj+yi*yj)+zi*zj, d2=(sqi+sqj)-2*dot, contract off -> same hit
//    set -> same output (absmax 0).
//  - Gather phase unchanged (WRITE_SIZE already minimal).

#define BB 4
#define NN 4096
#define KK 16
#define PLANE (NN * KK)   // 65536
#define NC 20
#define NCELLS (NC * NC * NC)   // 8000

__device__ __forceinline__ int cell1d(float v)
{
    int c = (int)floorf((v + 160.0f) * 0.0625f);
    c = c < 0 ? 0 : c;
    return c > (NC - 1) ? (NC - 1) : c;
}

// ---------- K1: P[b*N+j] = (x,y,z,sq) + per-cell histogram ----------
__global__ __launch_bounds__(256)
void build_soa(const float* __restrict__ xyz, float4* __restrict__ P,
               int* __restrict__ counts)
{
#pragma clang fp contract(off)
    const int g = blockIdx.x * 256 + threadIdx.x;      // 0..16383
    const float x = xyz[3 * g], y = xyz[3 * g + 1], z = xyz[3 * g + 2];
    const float sq = (x * x + y * y) + z * z;
    P[g] = make_float4(x, y, z, sq);
    const int c = (cell1d(z) * NC + cell1d(y)) * NC + cell1d(x);
    atomicAdd(&counts[(g >> 12) * NCELLS + c], 1);
}

// ---------- K2: exclusive scan of per-cell counts (1 block / batch) ----------
// Writes cellStart[c] (query read-only) and overwrites counts[c] with the same
// start value (scatter cursor).
__global__ __launch_bounds__(256)
void scan_cells(int* __restrict__ counts, int* __restrict__ cellStart)
{
    const int b = blockIdx.x;
    int* cnt = counts + b * NCELLS;
    int* cs  = cellStart + b * (NCELLS + 1);
    const int t = threadIdx.x;
    const int lane = t & 63, wave = t >> 6;

    const int c0 = t * 32;
    const int c1 = (c0 + 32 < NCELLS) ? c0 + 32 : NCELLS;
    int s = 0;
    for (int c = c0; c < c1; ++c) s += cnt[c];

    int x = s;                                    // inclusive scan across wave
#pragma unroll
    for (int off = 1; off < 64; off <<= 1) {
        const int u = __shfl_up(x, off, 64);
        if (lane >= off) x += u;
    }
    __shared__ int wsum[4];
    if (lane == 63) wsum[wave] = x;
    __syncthreads();
    int wb = 0;
    for (int w = 0; w < wave; ++w) wb += wsum[w];
    int acc = wb + x - s;                         // exclusive prefix of chunk

    for (int c = c0; c < c1; ++c) {
        const int v = cnt[c];
        cs[c]  = acc;
        cnt[c] = acc;
        acc += v;
    }
    if (t == 0) cs[NCELLS] = NN;
}

// ---------- K3: scatter points into cell-sorted order ----------
__global__ __launch_bounds__(256)
void scatter(const float4* __restrict__ P, int* __restrict__ cursor,
             float4* __restrict__ SP, int* __restrict__ SI)
{
    const int g = blockIdx.x * 256 + threadIdx.x;
    const float4 p = P[g];
    const int c = (cell1d(p.z) * NC + cell1d(p.y)) * NC + cell1d(p.x);
    const int b = g >> 12;
    const int slot = atomicAdd(&cursor[b * NCELLS + c], 1);
    SP[(b << 12) + slot] = p;
    SI[(b << 12) + slot] = g & (NN - 1);
}

// ---------- K4: fused grid ball query + gather ----------
// grid: 4096 blocks x 256 threads; block handles 4 consecutive points,
// wave w queries point p0+w via its 3x3x3 cell neighborhood.
__global__ __launch_bounds__(256, 4)
void query_gather(const float4* __restrict__ P, const float4* __restrict__ SP,
                  const int* __restrict__ SI, const int* __restrict__ CS,
                  const float* __restrict__ feat, float* __restrict__ out)
{
#pragma clang fp contract(off)
    __shared__ unsigned int mask[4][128];   // 4096-bit hit mask per point
    __shared__ int sids[4 * KK];

    const int beta = blockIdx.x;
    const int b    = beta >> 10;
    const int p0   = (beta & 1023) * 4;
    const int t    = threadIdx.x;
    const int lane = t & 63;
    const int wave = t >> 6;

    ((unsigned int*)mask)[t]       = 0u;
    ((unsigned int*)mask)[t + 256] = 0u;
    __syncthreads();

    const float4* Pb  = P  + (b << 12);
    const float4* Sb  = SP + (b << 12);
    const int*    Ib  = SI + (b << 12);
    const int*    csb = CS + b * (NCELLS + 1);

    const float4 pi = Pb[p0 + wave];

    // ---- query: scan 3x3x3 neighbor cells, set hit bits at original index ----
    {
        const float sqi = pi.w;
        unsigned int* m = mask[wave];
        const int cx = cell1d(pi.x), cy = cell1d(pi.y), cz = cell1d(pi.z);
        const int x0 = cx > 0 ? cx - 1 : 0;
        const int x1 = cx < NC - 1 ? cx + 1 : NC - 1;
        const int y0 = cy > 0 ? cy - 1 : 0;
        const int y1 = cy < NC - 1 ? cy + 1 : NC - 1;
        const int z0 = cz > 0 ? cz - 1 : 0;
        const int z1 = cz < NC - 1 ? cz + 1 : NC - 1;
        for (int zz = z0; zz <= z1; ++zz)
            for (int yy = y0; yy <= y1; ++yy) {
                const int cb = (zz * NC + yy) * NC;
                const int s  = csb[cb + x0];
                const int e  = csb[cb + x1 + 1];          // x-run is contiguous
                for (int k = s + lane; k < e; k += 64) {
                    const float4 a = Sb[k];
                    const float dot = (pi.x * a.x + pi.y * a.y) + pi.z * a.z;
                    const float d2  = (sqi + a.w) - 2.0f * dot;
                    if (d2 < 256.0f) {
                        const int j = Ib[k];
                        atomicOr(&m[j >> 5], 1u << (j & 31));
                    }
                }
            }
    }
    __syncthreads();

    // ---- rank extraction: lane l owns indices [64l, 64l+64) ----
    {
        const unsigned int* m = mask[wave];
        const unsigned int lo  = m[2 * lane];
        const unsigned int hiw = m[2 * lane + 1];
        const unsigned long long w = ((unsigned long long)hiw << 32) | lo;
        const int c = __popcll(w);
        int x = c;                                  // inclusive scan of counts
#pragma unroll
        for (int off = 1; off < 64; off <<= 1) {
            const int u = __shfl_up(x, off, 64);
            if (lane >= off) x += u;
        }
        const int cnt  = __shfl(x, 63, 64);         // total hits
        const int base = x - c;                     // hits before this lane

        int fj = 0x7fffffff;                        // global first hit
        if (w) fj = (lane << 6) + __builtin_ctzll(w);
        for (int off = 32; off; off >>= 1) {
            const int o = __shfl_xor(fj, off, 64);
            fj = fj < o ? fj : o;
        }

        int* row = sids + wave * KK;
        if (w && base <= 30 && base + c > 16) {     // lane covers ranks 16..30?
            unsigned long long ww = w;
            int r = base;
            while (ww) {
                if (r > 30) break;
                if (r >= 16) row[r - 15] = (lane << 6) + __builtin_ctzll(ww);
                ww &= ww - 1;
                ++r;
            }
        }
        const int hi = (cnt < 31 ? cnt : 31) - 16;
        if (lane < KK && (lane == 0 || lane > hi)) row[lane] = fj;
    }
    __syncthreads();

    // ---- gather phase: thread t -> output row (t&63), channel quarter (t>>6) ----
    const int rowi = t & 63;
    const int part = t >> 6;
    const int id   = sids[rowi];
    const int ob   = (beta & 1023) * 64 + rowi;

    if (part == 0) {                                // dilated_xyz [B,3,N,K]
        const float4 p = Pb[id];
        float* o0 = out + (size_t)b * 3 * PLANE + ob;
        o0[0]         = p.x;
        o0[PLANE]     = p.y;
        o0[2 * PLANE] = p.z;
    }

    // dilated_feature [B,64,N,K], channels [16*part, 16*part+16)
    const float4* frow = reinterpret_cast<const float4*>(feat + ((size_t)(b << 12) + id) * 64) + part * 4;
    float* o1 = out + (size_t)BB * 3 * PLANE + (size_t)b * 64 * PLANE
                    + (size_t)(part * 16) * PLANE + ob;
#pragma unroll
    for (int q = 0; q < 4; ++q) {
        const float4 v = frow[q];
        float* oc = o1 + (size_t)(4 * q) * PLANE;
        oc[0]         = v.x;
        oc[PLANE]     = v.y;
        oc[2 * PLANE] = v.z;
        oc[3 * PLANE] = v.w;
    }
}

extern "C" void kernel_launch(void* const* d_in, const int* in_sizes, int n_in,
                              void* d_out, int out_size, void* d_ws, size_t ws_size,
                              hipStream_t stream) {
    const float* xyz  = (const float*)d_in[0];
    const float* feat = (const float*)d_in[1];
    float* out = (float*)d_out;

    char* ws = (char*)d_ws;
    float4* P         = (float4*)(ws);                // 16384*16 = 262144
    float4* SP        = (float4*)(ws + 262144);       // 262144
    int*    SI        = (int*)   (ws + 524288);       // 65536
    int*    counts    = (int*)   (ws + 589824);       // 4*8000*4 = 128000 (pad to 131072)
    int*    cellStart = (int*)   (ws + 720896);       // 4*8001*4 = 128016  (total ~849 KB)

    hipMemsetAsync(counts, 0, BB * NCELLS * sizeof(int), stream);
    build_soa  <<<BB * NN / 256, 256, 0, stream>>>(xyz, P, counts);
    scan_cells <<<BB,            256, 0, stream>>>(counts, cellStart);
    scatter    <<<BB * NN / 256, 256, 0, stream>>>(P, counts, SP, SI);
    query_gather<<<BB * NN / 4,  256, 0, stream>>>(P, SP, SI, cellStart, feat, out);
}

// Round 2
// 115.410 us; speedup vs baseline: 1.1428x; 1.1428x over previous
//
#include <hip/hip_runtime.h>

// AnnularDilatedKNN: B=4, N=4096, C=64, SAMPLE=16, DILATED_RATE=2, r^2=256.
// Round 5: 2-dispatch grid-hash pipeline.
//  - K1 preprocess (4 blocks, 1/batch): LDS histogram (32KB) -> in-block scan
//    -> LDS-cursor scatter. Writes P (x,y,z,sq) and SP (x,y,z,bitcast idx).
//    No memset, no global atomics, no separate scan/scatter dispatches.
//  - K2 query_gather: per-point wave query over 3x3x3 cells; all 18 cellStart
//    loads issued up-front (unrolled, clamped -> duplicate rows harmless since
//    hits are an idempotent bitmask OR); 9 segments FLATTENED into one
//    lane-linear space via constant-indexed select chain so all 64 lanes stay
//    active. sq of candidates recomputed bit-identically ((x*x+y*y)+z*z,
//    contract off) so SP.w can carry the original index. Rank recovery via
//    4096-bit LDS mask + popcount scan (same as round 4, which passed).
//  - Gather phase unchanged (WRITE_SIZE already minimal).

#define BB 4
#define NN 4096
#define KK 16
#define PLANE (NN * KK)   // 65536
#define NC 20
#define NCELLS (NC * NC * NC)   // 8000

__device__ __forceinline__ int cell1d(float v)
{
    int c = (int)floorf((v + 160.0f) * 0.0625f);
    c = c < 0 ? 0 : c;
    return c > (NC - 1) ? (NC - 1) : c;
}

// ---------- K1: per-batch histogram -> scan -> scatter (1 block per batch) ----------
__global__ __launch_bounds__(256)
void preprocess(const float* __restrict__ xyz, float4* __restrict__ P,
                float4* __restrict__ SP, int* __restrict__ CS)
{
#pragma clang fp contract(off)
    __shared__ int hist[NCELLS];        // 32000 B
    __shared__ int wsum[4];

    const int b = blockIdx.x;
    const int t = threadIdx.x;
    const int lane = t & 63, wave = t >> 6;
    const float* xb = xyz + b * NN * 3;

    for (int c = t; c < NCELLS; c += 256) hist[c] = 0;
    __syncthreads();

    // pass 1: build P + LDS histogram
    for (int i = t; i < NN; i += 256) {
        const float x = xb[3 * i], y = xb[3 * i + 1], z = xb[3 * i + 2];
        const float sq = (x * x + y * y) + z * z;
        P[(b << 12) + i] = make_float4(x, y, z, sq);
        const int c = (cell1d(z) * NC + cell1d(y)) * NC + cell1d(x);
        atomicAdd(&hist[c], 1);
    }
    __syncthreads();

    // in-block exclusive scan; hist[c] becomes the scatter cursor
    const int c0 = t * 32;
    const int c1 = (c0 + 32 < NCELLS) ? c0 + 32 : NCELLS;
    int s = 0;
    for (int c = c0; c < c1; ++c) s += hist[c];
    int x = s;
#pragma unroll
    for (int off = 1; off < 64; off <<= 1) {
        const int u = __shfl_up(x, off, 64);
        if (lane >= off) x += u;
    }
    if (lane == 63) wsum[wave] = x;
    __syncthreads();
    int wb = 0;
    for (int w = 0; w < wave; ++w) wb += wsum[w];
    int acc = wb + x - s;

    int* cs = CS + b * (NCELLS + 1);
    for (int c = c0; c < c1; ++c) {
        const int v = hist[c];
        cs[c]   = acc;
        hist[c] = acc;
        acc += v;
    }
    if (t == 0) cs[NCELLS] = NN;
    __syncthreads();

    // pass 2: scatter into cell-sorted order; SP.w carries original index
    for (int i = t; i < NN; i += 256) {
        const float x = xb[3 * i], y = xb[3 * i + 1], z = xb[3 * i + 2];
        const int c = (cell1d(z) * NC + cell1d(y)) * NC + cell1d(x);
        const int slot = atomicAdd(&hist[c], 1);
        SP[(b << 12) + slot] = make_float4(x, y, z, __int_as_float(i));
    }
}

// ---------- K2: fused grid ball query + gather ----------
// grid: 4096 blocks x 256 threads; block handles 4 consecutive points,
// wave w queries point p0+w via its 3x3x3 cell neighborhood.
__global__ __launch_bounds__(256, 4)
void query_gather(const float4* __restrict__ P, const float4* __restrict__ SP,
                  const int* __restrict__ CS, const float* __restrict__ feat,
                  float* __restrict__ out)
{
#pragma clang fp contract(off)
    __shared__ unsigned int mask[4][128];   // 4096-bit hit mask per point
    __shared__ int sids[4 * KK];

    const int beta = blockIdx.x;
    const int b    = beta >> 10;
    const int p0   = (beta & 1023) * 4;
    const int t    = threadIdx.x;
    const int lane = t & 63;
    const int wave = t >> 6;

    ((unsigned int*)mask)[t]       = 0u;
    ((unsigned int*)mask)[t + 256] = 0u;
    __syncthreads();

    const float4* Pb  = P  + (b << 12);
    const float4* Sb  = SP + (b << 12);
    const int*    csb = CS + b * (NCELLS + 1);

    const float4 pi = Pb[p0 + wave];

    // ---- query: 3x3x3 neighbor cells, flattened candidate space ----
    {
        const float sqi = pi.w;
        unsigned int* m = mask[wave];
        const int cx = cell1d(pi.x), cy = cell1d(pi.y), cz = cell1d(pi.z);
        const int xlo = cx > 0 ? cx - 1 : 0;
        const int xhi = cx < NC - 1 ? cx + 1 : NC - 1;

        // issue all 18 segment-bound loads up-front (clamped dup rows are
        // harmless: mask OR is idempotent)
        int ss[9], se[9];
#pragma unroll
        for (int dz = 0; dz < 3; ++dz)
#pragma unroll
            for (int dy = 0; dy < 3; ++dy) {
                int zz = cz + dz - 1; zz = zz < 0 ? 0 : (zz > NC - 1 ? NC - 1 : zz);
                int yy = cy + dy - 1; yy = yy < 0 ? 0 : (yy > NC - 1 ? NC - 1 : yy);
                const int cb = (zz * NC + yy) * NC;
                ss[dz * 3 + dy] = csb[cb + xlo];
                se[dz * 3 + dy] = csb[cb + xhi + 1];   // x-run contiguous
            }

        // flatten: off[i] = start of segment i in lane-linear space,
        // base[i] = ss[i] - off[i]; all indices compile-time constant.
        int off[10], base[9];
        off[0] = 0;
#pragma unroll
        for (int i = 0; i < 9; ++i) {
            off[i + 1] = off[i] + (se[i] - ss[i]);
            base[i]    = ss[i] - off[i];
        }
        const int T = off[9];

        for (int u = lane; u < T; u += 64) {
            int bsel = base[0];
#pragma unroll
            for (int i = 1; i < 9; ++i) bsel = (u >= off[i]) ? base[i] : bsel;
            const float4 a = Sb[u + bsel];
            const float sqj = (a.x * a.x + a.y * a.y) + a.z * a.z;
            const float dot = (pi.x * a.x + pi.y * a.y) + pi.z * a.z;
            const float d2  = (sqi + sqj) - 2.0f * dot;
            if (d2 < 256.0f) {
                const int j = __float_as_int(a.w);
                atomicOr(&m[j >> 5], 1u << (j & 31));
            }
        }
    }
    __syncthreads();

    // ---- rank extraction: lane l owns indices [64l, 64l+64) ----
    {
        const unsigned int* m = mask[wave];
        const unsigned int lo  = m[2 * lane];
        const unsigned int hiw = m[2 * lane + 1];
        const unsigned long long w = ((unsigned long long)hiw << 32) | lo;
        const int c = __popcll(w);
        int x = c;                                  // inclusive scan of counts
#pragma unroll
        for (int off = 1; off < 64; off <<= 1) {
            const int u = __shfl_up(x, off, 64);
            if (lane >= off) x += u;
        }
        const int cnt  = __shfl(x, 63, 64);         // total hits
        const int base = x - c;                     // hits before this lane

        int fj = 0x7fffffff;                        // global first hit
        if (w) fj = (lane << 6) + __builtin_ctzll(w);
        for (int off = 32; off; off >>= 1) {
            const int o = __shfl_xor(fj, off, 64);
            fj = fj < o ? fj : o;
        }

        int* row = sids + wave * KK;
        if (w && base <= 30 && base + c > 16) {     // lane covers ranks 16..30?
            unsigned long long ww = w;
            int r = base;
            while (ww) {
                if (r > 30) break;
                if (r >= 16) row[r - 15] = (lane << 6) + __builtin_ctzll(ww);
                ww &= ww - 1;
                ++r;
            }
        }
        const int hi = (cnt < 31 ? cnt : 31) - 16;
        if (lane < KK && (lane == 0 || lane > hi)) row[lane] = fj;
    }
    __syncthreads();

    // ---- gather phase: thread t -> output row (t&63), channel quarter (t>>6) ----
    const int rowi = t & 63;
    const int part = t >> 6;
    const int id   = sids[rowi];
    const int ob   = (beta & 1023) * 64 + rowi;

    if (part == 0) {                                // dilated_xyz [B,3,N,K]
        const float4 p = Pb[id];
        float* o0 = out + (size_t)b * 3 * PLANE + ob;
        o0[0]         = p.x;
        o0[PLANE]     = p.y;
        o0[2 * PLANE] = p.z;
    }

    // dilated_feature [B,64,N,K], channels [16*part, 16*part+16)
    const float4* frow = reinterpret_cast<const float4*>(feat + ((size_t)(b << 12) + id) * 64) + part * 4;
    float* o1 = out + (size_t)BB * 3 * PLANE + (size_t)b * 64 * PLANE
                    + (size_t)(part * 16) * PLANE + ob;
#pragma unroll
    for (int q = 0; q < 4; ++q) {
        const float4 v = frow[q];
        float* oc = o1 + (size_t)(4 * q) * PLANE;
        oc[0]         = v.x;
        oc[PLANE]     = v.y;
        oc[2 * PLANE] = v.z;
        oc[3 * PLANE] = v.w;
    }
}

extern "C" void kernel_launch(void* const* d_in, const int* in_sizes, int n_in,
                              void* d_out, int out_size, void* d_ws, size_t ws_size,
                              hipStream_t stream) {
    const float* xyz  = (const float*)d_in[0];
    const float* feat = (const float*)d_in[1];
    float* out = (float*)d_out;

    char* ws = (char*)d_ws;
    float4* P         = (float4*)(ws);                // 16384*16 = 262144
    float4* SP        = (float4*)(ws + 262144);       // 262144
    int*    CS        = (int*)   (ws + 524288);       // 4*8001*4 = 128016 (total ~652 KB)

    preprocess  <<<BB,           256, 0, stream>>>(xyz, P, SP, CS);
    query_gather<<<BB * NN / 4,  256, 0, stream>>>(P, SP, CS, feat, out);
}